// Round 1
// baseline (129.109 us; speedup 1.0000x reference)
//
#include <hip/hip_runtime.h>
#include <cmath>

// Problem constants (from reference):
//   x: (512, 128) fp32, sort per column, 1000-pt trapezoid Beta(0.6,0.4) CDF,
//   loss = sum((pcdf - ecdf)^2)/512, scalar fp32 output.
#define N_ROWS 512
#define N_COLS 128
#define N_ELEM (N_ROWS * N_COLS)
constexpr float EPSF = 1e-10f;

// -------- Kernel 1: bitonic sort each column (512 elements) in LDS ---------
__global__ __launch_bounds__(512) void sort_cols(const float* __restrict__ x,
                                                 float* __restrict__ sorted) {
    __shared__ float sd[N_ROWS];
    const int tid = threadIdx.x;
    const int col = blockIdx.x;
    // column col: x[i*128 + col]
    sd[tid] = x[tid * N_COLS + col];
    __syncthreads();
    for (int k = 2; k <= N_ROWS; k <<= 1) {
        for (int st = k >> 1; st > 0; st >>= 1) {
            int partner = tid ^ st;
            if (partner > tid) {
                float a = sd[tid];
                float b = sd[partner];
                bool asc = ((tid & k) == 0);
                if ((a > b) == asc) {  // out of order -> swap
                    sd[tid] = b;
                    sd[partner] = a;
                }
            }
            __syncthreads();
        }
    }
    // sorted layout: [col][rank] = sorted[col*512 + rank]
    sorted[col * N_ROWS + tid] = sd[tid];
}

// -------- Kernel 2: one wave per element; lanes parallelize over t ----------
// pcdf(s) = h * (0.5*p(x_1) + sum_{t=2..998} p(x_t) + 0.5*p(x_999)),
//   x_t = EPS + (t/999)*(s-EPS), h = (s-EPS)/999
// p(x) = exp((a-1)ln x + (b-1)ln(1-x) - betaln), a=0.6, b=0.4
__global__ __launch_bounds__(256) void pcdf_loss(const float* __restrict__ sorted,
                                                 float* __restrict__ partials,
                                                 float neg_betaln) {
    const int lane = threadIdx.x & 63;
    const int wv   = threadIdx.x >> 6;                 // wave in block (0..3)
    const int e    = (blockIdx.x << 2) + wv;           // element id 0..65535
    const float s  = sorted[e];                        // broadcast load
    const float sm = s - EPSF;

    float acc = 0.0f;
    const float inv999 = 1.0f / 999.0f;
    for (int t = 1 + lane; t <= 999; t += 64) {
        float u  = (float)t * inv999;
        float xv = fmaf(u, sm, EPSF);
        float lx = __logf(xv);
        float l1 = __logf(1.0f - xv);
        float arg = fmaf(-0.4f, lx, fmaf(-0.6f, l1, neg_betaln));
        float p = __expf(arg);
        acc += (t == 1 || t == 999) ? 0.5f * p : p;    // trapezoid end weights
    }
    // wave (64-lane) reduction
    #pragma unroll
    for (int off = 32; off > 0; off >>= 1)
        acc += __shfl_down(acc, off);

    __shared__ float blk[4];
    if (lane == 0) {
        float h    = sm * inv999;
        float pcdf = h * acc;
        int   i    = e & (N_ROWS - 1);                 // rank within column
        float ecdf = (float)(i + 1) * (1.0f / 513.0f); // (i+1)/(n+1)
        float d    = pcdf - ecdf;
        blk[wv] = d * d;
    }
    __syncthreads();
    if (threadIdx.x == 0)
        partials[blockIdx.x] = blk[0] + blk[1] + blk[2] + blk[3];
}

// -------- Kernel 3: reduce 16384 block partials -> loss ---------------------
__global__ __launch_bounds__(256) void reduce_partials(const float* __restrict__ partials,
                                                       float* __restrict__ out, int n) {
    float acc = 0.0f;
    for (int idx = threadIdx.x; idx < n; idx += 256)
        acc += partials[idx];
    #pragma unroll
    for (int off = 32; off > 0; off >>= 1)
        acc += __shfl_down(acc, off);
    __shared__ float w[4];
    const int lane = threadIdx.x & 63;
    const int wv   = threadIdx.x >> 6;
    if (lane == 0) w[wv] = acc;
    __syncthreads();
    if (threadIdx.x == 0)
        out[0] = (w[0] + w[1] + w[2] + w[3]) * (1.0f / (float)N_ROWS);
}

extern "C" void kernel_launch(void* const* d_in, const int* in_sizes, int n_in,
                              void* d_out, int out_size, void* d_ws, size_t ws_size,
                              hipStream_t stream) {
    const float* x = (const float*)d_in[0];
    float* out = (float*)d_out;
    float* ws = (float*)d_ws;
    float* sorted   = ws;            // 65536 floats
    float* partials = ws + N_ELEM;   // 16384 floats

    // BETALN = lgamma(0.6) + lgamma(0.4) - lgamma(1.0)  (~1.1949129)
    double betaln = lgamma(0.6) + lgamma(0.4) - lgamma(1.0);
    float neg_betaln = (float)(-betaln);

    sort_cols<<<N_COLS, N_ROWS, 0, stream>>>(x, sorted);

    const int blocks2 = N_ELEM / 4;  // 4 waves (elements) per 256-thread block
    pcdf_loss<<<blocks2, 256, 0, stream>>>(sorted, partials, neg_betaln);

    reduce_partials<<<1, 256, 0, stream>>>(partials, out, blocks2);
}

// Round 3
// 97.005 us; speedup vs baseline: 1.3310x; 1.3310x over previous
//
#include <hip/hip_runtime.h>
#include <cmath>

// x: (512,128) fp32. Per column: sort 512, 1000-pt trapezoid Beta(0.6,0.4) CDF,
// loss = sum((pcdf-ecdf)^2)/512.
// Factorization: p(x_t) = x_t^{-0.4}(1-x_t)^{-0.6}/B, x_t = u_t*sm (EPS dropped in
// the x^{-0.4} factor only -- worst-case loss impact ~1e-8, threshold 4.9e-2).
// pcdf = sm^{0.6}/(999 B) * sum_t A_t * (1-u_t*sm)^{-0.6},  A_t = u_t^{-0.4}
// (end weights 0.5 folded into A_1, A_999; table zero-padded to 1056).
#define N_ROWS 512
#define N_COLS 128
#define N_ELEM (N_ROWS * N_COLS)
#define TBL_N 1056
#define PCDF_BLOCKS (N_ELEM / 16)   // 4096: 4 waves/block x 4 elements/wave

// -------- Kernel 1: register bitonic sort per column + table fill ----------
__global__ __launch_bounds__(512) void sort_cols(const float* __restrict__ x,
                                                 float* __restrict__ sorted,
                                                 float* __restrict__ tableA) {
    __shared__ float sd[N_ROWS];
    const int tid = threadIdx.x;
    const int col = blockIdx.x;
    float v = x[tid * N_COLS + col];
    for (int k = 2; k <= N_ROWS; k <<= 1) {
        for (int j = k >> 1; j > 0; j >>= 1) {
            float pv;
            if (j >= 64) {                 // cross-wave: go through LDS
                __syncthreads();
                sd[tid] = v;
                __syncthreads();
                pv = sd[tid ^ j];
            } else {                       // in-wave: shuffle (no barrier)
                pv = __shfl_xor(v, j, 64);
            }
            const bool lower = (tid & j) == 0;
            const bool asc   = (tid & k) == 0;
            v = (lower == asc) ? fminf(v, pv) : fmaxf(v, pv);
        }
    }
    sorted[col * N_ROWS + tid] = v;        // [col][rank]
    if (col == 0) {                        // block 0 also fills the A_t table
        for (int t = tid; t < TBL_N; t += N_ROWS) {
            float a = 0.0f;
            if (t >= 1 && t <= 999) {
                float u = (float)t * (1.0f / 999.0f);
                a = __expf(-0.4f * __logf(u));         // u^{-0.4}
                if (t == 1 || t == 999) a *= 0.5f;
            }
            tableA[t] = a;
        }
    }
}

// -------- Kernel 2: pcdf + squared-diff; 4 elements per wave ---------------
__global__ __launch_bounds__(256) void pcdf_loss(const float* __restrict__ sorted,
                                                 const float* __restrict__ tableA,
                                                 float* __restrict__ partials,
                                                 float invB999) {
    const int lane  = threadIdx.x & 63;
    const int wv    = threadIdx.x >> 6;
    const int ebase = blockIdx.x * 16 + wv * 4;
    const float inv999 = 1.0f / 999.0f;

    float wsum = 0.0f;
    #pragma unroll
    for (int q = 0; q < 4; ++q) {
        const int e = ebase + q;
        const float s  = sorted[e];        // wave-uniform broadcast load
        const float sm = s - 1e-10f;
        float acc = 0.0f;
        float tf = (float)(1 + lane);
        #pragma unroll
        for (int it = 0; it < 16; ++it) {
            float a  = tableA[1 + lane + 64 * it];     // L1-resident 4KB table
            float u  = tf * inv999;
            float om = fmaf(-u, sm, 1.0f);             // 1 - x_t
            om = fmaxf(om, 1e-30f);                    // keep padded lanes finite
            float p  = __expf(-0.6f * __logf(om));     // (1-x_t)^{-0.6}
            acc = fmaf(a, p, acc);
            tf += 64.0f;
        }
        #pragma unroll
        for (int off = 32; off > 0; off >>= 1)
            acc += __shfl_down(acc, off);
        if (lane == 0) {
            float C    = __expf(0.6f * __logf(sm)) * invB999;  // sm^0.6/(999 B)
            float pcdf = C * acc;
            float ecdf = (float)((e & (N_ROWS - 1)) + 1) * (1.0f / 513.0f);
            float d    = pcdf - ecdf;
            wsum += d * d;
        }
    }
    __shared__ float blk[4];
    if (lane == 0) blk[wv] = wsum;
    __syncthreads();
    if (threadIdx.x == 0)
        partials[blockIdx.x] = blk[0] + blk[1] + blk[2] + blk[3];
}

// -------- Kernel 3: reduce 4096 partials -> loss ---------------------------
__global__ __launch_bounds__(256) void reduce_partials(const float* __restrict__ partials,
                                                       float* __restrict__ out, int n) {
    float acc = 0.0f;
    for (int idx = threadIdx.x; idx < n; idx += 256)
        acc += partials[idx];
    #pragma unroll
    for (int off = 32; off > 0; off >>= 1)
        acc += __shfl_down(acc, off);
    __shared__ float w[4];
    const int lane = threadIdx.x & 63;
    const int wv   = threadIdx.x >> 6;
    if (lane == 0) w[wv] = acc;
    __syncthreads();
    if (threadIdx.x == 0)
        out[0] = (w[0] + w[1] + w[2] + w[3]) * (1.0f / (float)N_ROWS);
}

extern "C" void kernel_launch(void* const* d_in, const int* in_sizes, int n_in,
                              void* d_out, int out_size, void* d_ws, size_t ws_size,
                              hipStream_t stream) {
    const float* x = (const float*)d_in[0];
    float* out = (float*)d_out;
    float* ws = (float*)d_ws;
    float* sorted   = ws;                       // 65536 floats
    float* partials = ws + N_ELEM;              // 4096 floats
    float* tableA   = ws + N_ELEM + PCDF_BLOCKS;// 1056 floats

    // B = exp(lgamma(.6)+lgamma(.4)-lgamma(1)) ;  invB999 = 1/(999*B)
    double B = exp(lgamma(0.6) + lgamma(0.4) - lgamma(1.0));
    float invB999 = (float)(1.0 / (999.0 * B));

    sort_cols<<<N_COLS, N_ROWS, 0, stream>>>(x, sorted, tableA);
    pcdf_loss<<<PCDF_BLOCKS, 256, 0, stream>>>(sorted, tableA, partials, invB999);
    reduce_partials<<<1, 256, 0, stream>>>(partials, out, PCDF_BLOCKS);
}

// Round 4
// 68.316 us; speedup vs baseline: 1.8899x; 1.4200x over previous
//
#include <hip/hip_runtime.h>
#include <cmath>

// x: (512,128) fp32. Per column: sort 512; reference computes a 999-pt trapezoid
// of the Beta(0.6,0.4) pdf from x1=EPS+h to s (h=(s-EPS)/999, t=0 dropped);
// loss = sum((pcdf-ecdf)^2)/512, threshold 4.875e-2 absolute.
//
// Analytic reproduction of the trapezoid (error << 1e-3 per element):
//   T(s) = I_s(0.6,0.4)                      exact regularized incomplete beta (CF)
//        - c_head * x1^0.6                   missing head [0,x1] minus left-end
//                                            trapezoid excess: c_head = 1/(0.6B) - 0.03185/B
//        + D_R                               right-end trap-minus-exact, last 8
//                                            intervals, computed explicitly
// D_R = s^{-0.4}/B * sum_{j=1..8} [ h/2 (w_{j-1}^{-.6}+w_j^{-.6}) - (w_j^{.4}-w_{j-1}^{.4})/0.4 ],
//   w_j = (1-s) + j*h.  Middle-region residual <= 3e-5/element.
#define N_ROWS 512
#define N_COLS 128

__device__ __forceinline__ float betacf(float a, float b, float x) {
    // Numerical Recipes continued fraction (modified Lentz), 16 double-steps.
    float qab = a + b, qap = a + 1.0f, qam = a - 1.0f;
    float c = 1.0f;
    float d = 1.0f - qab * x / qap;
    if (fabsf(d) < 1e-30f) d = 1e-30f;
    d = 1.0f / d;
    float h = d;
    #pragma unroll
    for (int m = 1; m <= 16; ++m) {
        float fm = (float)m, m2 = 2.0f * fm;
        float aa = fm * (b - fm) * x / ((qam + m2) * (a + m2));
        d = 1.0f + aa * d; if (fabsf(d) < 1e-30f) d = 1e-30f;
        c = 1.0f + aa / c; if (fabsf(c) < 1e-30f) c = 1e-30f;
        d = 1.0f / d;
        h *= d * c;
        aa = -(a + fm) * (qab + fm) * x / ((a + m2) * (qap + m2));
        d = 1.0f + aa * d; if (fabsf(d) < 1e-30f) d = 1e-30f;
        c = 1.0f + aa / c; if (fabsf(c) < 1e-30f) c = 1e-30f;
        d = 1.0f / d;
        h *= d * c;
    }
    return h;
}

// -------- Kernel 1: bitonic sort per column fused with per-element pcdf-loss
__global__ __launch_bounds__(512) void sort_loss(const float* __restrict__ x,
                                                 float* __restrict__ partials,
                                                 float lnB, float invB, float c_head) {
    __shared__ float sd[N_ROWS];
    const int tid = threadIdx.x;
    const int col = blockIdx.x;
    float v = x[tid * N_COLS + col];
    for (int k = 2; k <= N_ROWS; k <<= 1) {
        for (int j = k >> 1; j > 0; j >>= 1) {
            float pv;
            if (j >= 64) {                 // cross-wave: via LDS
                __syncthreads();
                sd[tid] = v;
                __syncthreads();
                pv = sd[tid ^ j];
            } else {                       // in-wave: shuffle
                pv = __shfl_xor(v, j, 64);
            }
            const bool lower = (tid & j) == 0;
            const bool asc   = (tid & k) == 0;
            v = (lower == asc) ? fminf(v, pv) : fmaxf(v, pv);
        }
    }
    // v = sorted value at rank `tid` of column `col`.
    const float s  = fmaxf(v, 1e-30f);
    const float sm = s - 1e-10f;
    const float h  = sm * (1.0f / 999.0f);
    const float x1 = 1e-10f + h;

    // exact regularized incomplete beta I_s(0.6,0.4)
    const float ls  = __logf(s);
    const float om  = fmaxf(1.0f - s, 1e-30f);
    const float lom = __logf(om);
    const float bt  = __expf(fmaf(0.6f, ls, fmaf(0.4f, lom, -lnB)));
    float I;
    if (s < 0.53333333f)
        I = bt * betacf(0.6f, 0.4f, s) * (1.0f / 0.6f);
    else
        I = 1.0f - bt * betacf(0.4f, 0.6f, om) * (1.0f / 0.4f);

    // head correction
    const float head = c_head * __expf(0.6f * __logf(x1));

    // right-end trapezoid-vs-exact, last 8 intervals
    const float sm04 = __expf(-0.4f * ls);             // s^{-0.4}
    float wp      = om;                                // w_0 = 1 - s
    float wp_m06  = __expf(-0.6f * __logf(wp));
    float wp_p04  = wp * wp_m06;                       // w^{0.4}
    float dr = 0.0f;
    #pragma unroll
    for (int j = 1; j <= 8; ++j) {
        float w    = fmaf((float)j, h, om);
        float wm06 = __expf(-0.6f * __logf(w));
        float wp04 = w * wm06;
        float trap = 0.5f * h * (wp_m06 + wm06);
        float ex   = (wp04 - wp_p04) * 2.5f;           // /0.4
        dr += trap - ex;
        wp_m06 = wm06; wp_p04 = wp04;
    }
    dr *= sm04 * invB;

    const float T    = I - head + dr;
    const float ecdf = (float)(tid + 1) * (1.0f / 513.0f);
    const float d    = T - ecdf;
    float val = d * d;

    // block reduction (8 waves)
    #pragma unroll
    for (int off = 32; off > 0; off >>= 1)
        val += __shfl_down(val, off);
    __syncthreads();                                   // sd reuse
    if ((tid & 63) == 0) sd[tid >> 6] = val;
    __syncthreads();
    if (tid == 0) {
        float bs = 0.0f;
        #pragma unroll
        for (int w = 0; w < 8; ++w) bs += sd[w];
        partials[col] = bs;
    }
}

// -------- Kernel 2: reduce 128 partials -> loss -----------------------------
__global__ __launch_bounds__(64) void reduce_partials(const float* __restrict__ partials,
                                                      float* __restrict__ out) {
    float acc = partials[threadIdx.x] + partials[threadIdx.x + 64];
    #pragma unroll
    for (int off = 32; off > 0; off >>= 1)
        acc += __shfl_down(acc, off);
    if (threadIdx.x == 0)
        out[0] = acc * (1.0f / (float)N_ROWS);
}

extern "C" void kernel_launch(void* const* d_in, const int* in_sizes, int n_in,
                              void* d_out, int out_size, void* d_ws, size_t ws_size,
                              hipStream_t stream) {
    const float* x = (const float*)d_in[0];
    float* out = (float*)d_out;
    float* partials = (float*)d_ws;   // 128 floats

    const double B = exp(lgamma(0.6) + lgamma(0.4) - lgamma(1.0));  // 3.3034443
    const float lnB    = (float)log(B);
    const float invB   = (float)(1.0 / B);
    // head coeff: I(x1) ~ x1^0.6/(0.6B) minus left-end trap excess 0.03185*x1^0.6/B
    const float c_head = (float)(1.0 / (0.6 * B) - 0.03185 / B);

    sort_loss<<<N_COLS, N_ROWS, 0, stream>>>(x, partials, lnB, invB, c_head);
    reduce_partials<<<1, 64, 0, stream>>>(partials, out);
}